// Round 3
// baseline (593.302 us; speedup 1.0000x reference)
//
#include <hip/hip_runtime.h>
#include <math.h>

#define N_NODES 50000
#define N_EDGES 200000
#define N_GRAPHS 1024
#define DIM 24
#define EF 8
#define EH 128
#define DD 576   // 24*24

typedef __attribute__((ext_vector_type(8))) short short8;
typedef __attribute__((ext_vector_type(4))) float float4e;

// ---------- helpers ----------
static __device__ __forceinline__ unsigned short f2bf(float f) {
    union { float f; unsigned int u; } v; v.f = f;
    unsigned int u = v.u;
    u += ((u >> 16) & 1u) + 0x7FFFu;   // RNE
    return (unsigned short)(u >> 16);
}
static __device__ __forceinline__ float sigm(float x) { return 1.0f / (1.0f + expf(-x)); }

static __device__ __forceinline__ void gl_lds16(const unsigned short* g, unsigned short* l) {
    // async global->LDS DMA, 16B per lane, LDS dest = wave-uniform base + lane*16
    __builtin_amdgcn_global_load_lds((const unsigned int*)g, (unsigned int*)l, 16, 0, 0);
}

// ---------- deg (in-degree per node) ----------
__global__ void deg_kernel(const int* __restrict__ dst, int* __restrict__ deg) {
    int i = blockIdx.x * blockDim.x + threadIdx.x;
    if (i < N_EDGES) atomicAdd(&deg[dst[i]], 1);
}

// ---------- w2 swizzle + bf16 for DMA-able, conflict-free LDS B tiles ----------
// w2s layout: [chunk 4][ks 4][nn 144][quad 4][kk 8]  (chunk = 144-col slice, k = ks*32+quad*8+kk)
// -> each chunk is a contiguous 36,864B block; a B-fragment ds_read_b128 is a
//    perfectly contiguous 1024B wave access (bank-conflict-free).
__global__ __launch_bounds__(256) void w2s_kernel(const float* __restrict__ w2,
                                                  unsigned short* __restrict__ w2s) {
    int idx = blockIdx.x * 256 + threadIdx.x;   // idx = n*128 + k
    if (idx >= DD * EH) return;
    int n = idx >> 7, k = idx & 127;
    int c = n / 144, nn = n % 144;
    int ks = k >> 5, q = (k >> 3) & 3, kk = k & 7;
    size_t swz = ((size_t)((c * 4 + ks) * 144 + nn) * 4 + q) * 8 + kk;
    w2s[swz] = f2bf(w2[(size_t)k * DD + n]);
}

// ---------- fused NNConv message kernel: NO W materialization ----------
// grid 3125, block 256 (4 waves). Per block: 64 edges.
//   stage A: h = relu(ea@w1+b1) -> LDS bf16, layout [ks 4][e 64][quad 4][kk 8]
//   loop 4 chunks of 144 cols:
//     B chunk (36,864B) DMA'd from w2s (L2-hot, 144KB total) via global_load_lds
//     k-loop: 16x16x32 bf16 MFMA, wave = 1 m-tile x 9 n-tiles, acc seeded with b2
//     bounce acc (f32!) into same LDS buffer as C[64][148] (pad 148 breaks bank alias)
//     matvec: msg[e][o] += sum_i x[src[e]][i] * C[e][i*24+o]  (6 msg regs/thread)
//   epilogue: 6 atomicAdd per thread into agg.
// Replaces gemm_w + msg (690MB of HBM W traffic -> ~460MB of L2 traffic).
__global__ __launch_bounds__(256) void conv_kernel(
    const float* __restrict__ x, const float* __restrict__ ea,
    const float* __restrict__ w1, const float* __restrict__ b1,
    const unsigned short* __restrict__ w2s, const float* __restrict__ b2,
    const int* __restrict__ src, const int* __restrict__ dst,
    float* __restrict__ agg)
{
    __shared__ unsigned short Bs[18944];   // 37,888B: B chunk (first 36,864B) / C bounce [64][148] f32
    __shared__ unsigned short As[8192];    // 16,384B: A tile  [ks][e][quad][kk]
    __shared__ float xs[64][24];           //  6,144B: gathered x[src[e]]

    const int t  = threadIdx.x;
    const int e0 = blockIdx.x * 64;

    // ---- issue DMA of B chunk 0 first (latency hides under stage A) ----
    {
        const unsigned short* gsrc = w2s + (size_t)t * 8;
        unsigned short* lbase = Bs + (t >> 6) * 512;
        #pragma unroll
        for (int r = 0; r < 9; ++r)
            gl_lds16(gsrc + r * 2048, lbase + r * 2048);
    }

    // ---- gather x[src[e]] into LDS ----
    for (int idx = t; idx < 384; idx += 256) {
        int el = idx / 6, j4 = (idx % 6) * 4;
        int s = src[e0 + el];
        *(float4*)&xs[el][j4] = *(const float4*)(x + (size_t)s * DIM + j4);
    }

    // ---- stage A: h = relu(ea@w1+b1), 64 edges x 128 hid ----
    {
        const int s   = t & 31;          // k-slice: k = s*4 .. s*4+3
        const int eb  = (t >> 5) * 8;    // 8 edges starting here
        const int ksa = s >> 3, qa = (s >> 1) & 3, kk0 = (s & 1) * 4;
        char* Ab = (char*)As + ksa * 4096 + qa * 16 + kk0 * 2;
        float wv[EF][4];
        #pragma unroll
        for (int j = 0; j < EF; ++j) {
            float4 v = *(const float4*)(w1 + j * EH + s * 4);
            wv[j][0] = v.x; wv[j][1] = v.y; wv[j][2] = v.z; wv[j][3] = v.w;
        }
        float4 bv = *(const float4*)(b1 + s * 4);
        const float bvv[4] = {bv.x, bv.y, bv.z, bv.w};
        #pragma unroll
        for (int e = 0; e < 8; ++e) {
            const float* ear = ea + (size_t)(e0 + eb + e) * EF;
            float4 a0 = *(const float4*)ear;
            float4 a1 = *(const float4*)(ear + 4);
            const float av[EF] = {a0.x, a0.y, a0.z, a0.w, a1.x, a1.y, a1.z, a1.w};
            float r[4] = {bvv[0], bvv[1], bvv[2], bvv[3]};
            #pragma unroll
            for (int j = 0; j < EF; ++j)
                #pragma unroll
                for (int c4 = 0; c4 < 4; ++c4)
                    r[c4] = fmaf(av[j], wv[j][c4], r[c4]);
            ushort4 hq;
            hq.x = f2bf(fmaxf(r[0], 0.0f));
            hq.y = f2bf(fmaxf(r[1], 0.0f));
            hq.z = f2bf(fmaxf(r[2], 0.0f));
            hq.w = f2bf(fmaxf(r[3], 0.0f));
            *(ushort4*)(Ab + (size_t)(eb + e) * 64) = hq;
        }
    }

    const int lane = t & 63;
    const int wave = t >> 6;         // m-tile owner (16 edges)
    const int l16  = lane & 15;
    const int quad = lane >> 4;

    // bias values for all chunks (L2-hot scalar loads)
    float b2v[4][9];
    #pragma unroll
    for (int c = 0; c < 4; ++c)
        #pragma unroll
        for (int j = 0; j < 9; ++j)
            b2v[c][j] = b2[c * 144 + j * 16 + l16];

    __syncthreads();   // As + xs written, DMA chunk 0 complete (vmcnt drained by barrier)

    // ---- A fragments: persist across all chunks (k range is chunk-invariant) ----
    short8 af[4];
    #pragma unroll
    for (int ks = 0; ks < 4; ++ks)
        af[ks] = *(const short8*)((const char*)As + ks * 4096 + (wave * 16 + l16) * 64 + quad * 16);

    // matvec mapping: thread = (edge me, o-quarter oq -> 6 outputs)
    const int me = t >> 2, oq = t & 3;
    float msg[6] = {0.f, 0.f, 0.f, 0.f, 0.f, 0.f};
    float* Cs = (float*)Bs;          // C bounce view, stride 148 floats

    for (int c = 0; c < 4; ++c) {
        // ---- k-loop: 9 n-tiles x 4 k-steps ----
        float4e acc[9];
        #pragma unroll
        for (int j = 0; j < 9; ++j) {
            float bb = b2v[c][j];
            float4e v = {bb, bb, bb, bb};
            acc[j] = v;
        }
        #pragma unroll
        for (int j = 0; j < 9; ++j) {
            const char* Bp = (const char*)Bs + (j * 16 + l16) * 64 + quad * 16;
            #pragma unroll
            for (int ks = 0; ks < 4; ++ks) {
                short8 b = *(const short8*)(Bp + ks * 9216);
                acc[j] = __builtin_amdgcn_mfma_f32_16x16x32_bf16(af[ks], b, acc[j], 0, 0, 0);
            }
        }
        __syncthreads();   // all waves done reading this B chunk

        // ---- bounce acc -> Cs[64][148] f32 (row = quad*4+r, col = j*16+l16) ----
        #pragma unroll
        for (int j = 0; j < 9; ++j) {
            const int cc = j * 16 + l16;
            #pragma unroll
            for (int r = 0; r < 4; ++r)
                Cs[(wave * 16 + quad * 4 + r) * 148 + cc] = acc[j][r];
        }
        __syncthreads();

        // ---- matvec partial: msg[o] += sum_{i in chunk} x[i] * C[e][i*24+o] ----
        const float* Crow = Cs + me * 148 + oq * 6;
        #pragma unroll
        for (int i6 = 0; i6 < 6; ++i6) {
            float xv = xs[me][c * 6 + i6];
            const float* Cr = Crow + i6 * 24;
            #pragma unroll
            for (int p = 0; p < 3; ++p) {
                float2 cv = *(const float2*)(Cr + p * 2);
                msg[p * 2]     = fmaf(cv.x, xv, msg[p * 2]);
                msg[p * 2 + 1] = fmaf(cv.y, xv, msg[p * 2 + 1]);
            }
        }
        __syncthreads();   // Cs reads done before next DMA overwrites

        if (c < 3) {
            const unsigned short* gsrc = w2s + (size_t)(c + 1) * 18432 + (size_t)t * 8;
            unsigned short* lbase = Bs + (t >> 6) * 512;
            #pragma unroll
            for (int r = 0; r < 9; ++r)
                gl_lds16(gsrc + r * 2048, lbase + r * 2048);
            __syncthreads();   // DMA complete (barrier drains vmcnt)
        }
    }

    // ---- scatter: 6 atomics per thread ----
    const int de = dst[e0 + me];
    #pragma unroll
    for (int o6 = 0; o6 < 6; ++o6)
        atomicAdd(&agg[(size_t)de * DIM + oq * 6 + o6], msg[o6]);
}

// ---------- combine: x_out = [relu](agg/max(deg,1) + x_in@root + bias) ----------
__global__ void combine_kernel(
    const float* __restrict__ x_in, const float* __restrict__ agg,
    const int* __restrict__ deg, const float* __restrict__ root,
    const float* __restrict__ bias, float* __restrict__ x_out, int do_relu)
{
    int t = blockIdx.x * blockDim.x + threadIdx.x;
    if (t >= N_NODES * DIM) return;
    int v = t / DIM, o = t % DIM;
    int dg = deg[v];
    float d = dg > 0 ? (float)dg : 1.0f;
    float a = agg[t] / d + bias[o];
    const float* xr = x_in + (size_t)v * DIM;
    #pragma unroll
    for (int i = 0; i < DIM; ++i) a = fmaf(xr[i], root[i * DIM + o], a);
    x_out[t] = do_relu ? fmaxf(a, 0.0f) : a;
}

// ---------- Set2Set LSTM step: one thread per (graph, d) ----------
__global__ void lstm_kernel(
    const float* __restrict__ q_star, const float* __restrict__ h_in,
    const float* __restrict__ c_in, const float* __restrict__ w_ih,
    const float* __restrict__ w_hh, const float* __restrict__ b_ih,
    const float* __restrict__ b_hh, float* __restrict__ h_out,
    float* __restrict__ c_out)
{
    int t = blockIdx.x * blockDim.x + threadIdx.x;
    if (t >= N_GRAPHS * DIM) return;
    int g = t / DIM, d = t % DIM;
    const float* qs = q_star + (size_t)g * 48;
    const float* hv = h_in + (size_t)g * DIM;
    float gate[4];
    #pragma unroll
    for (int r4 = 0; r4 < 4; ++r4) {
        int r = r4 * DIM + d;
        float a = b_ih[r] + b_hh[r];
        const float* wi = w_ih + (size_t)r * 48;
        const float* wh = w_hh + (size_t)r * DIM;
        for (int j = 0; j < 48; ++j) a = fmaf(qs[j], wi[j], a);
        #pragma unroll
        for (int j = 0; j < DIM; ++j) a = fmaf(hv[j], wh[j], a);
        gate[r4] = a;
    }
    float c = sigm(gate[1]) * c_in[t] + sigm(gate[0]) * tanhf(gate[2]);
    h_out[t] = sigm(gate[3]) * tanhf(c);
    c_out[t] = c;
}

// ---------- per-graph attention + readout (batch sorted -> binary search) ----------
__global__ __launch_bounds__(64) void attn_kernel(
    const float* __restrict__ x, const int* __restrict__ batch,
    const float* __restrict__ h, float* __restrict__ q_star,
    float* __restrict__ e_buf)
{
    const int g = blockIdx.x;
    const int t = threadIdx.x;
    __shared__ int s_lo, s_hi;
    __shared__ float qs[DIM];
    if (t == 0) {
        int lo = 0, hi = N_NODES;
        while (lo < hi) { int m = (lo + hi) >> 1; if (batch[m] < g) lo = m + 1; else hi = m; }
        s_lo = lo;
        int lo2 = lo; hi = N_NODES;
        while (lo2 < hi) { int m = (lo2 + hi) >> 1; if (batch[m] <= g) lo2 = m + 1; else hi = m; }
        s_hi = lo2;
    }
    if (t < DIM) qs[t] = h[(size_t)g * DIM + t];
    __syncthreads();
    const int lo = s_lo, hi = s_hi;

    float mx = -INFINITY;
    for (int n = lo + t; n < hi; n += 64) {
        const float* xr = x + (size_t)n * DIM;
        float e = 0.0f;
        #pragma unroll
        for (int d = 0; d < DIM; ++d) e = fmaf(xr[d], qs[d], e);
        e_buf[n] = e;
        mx = fmaxf(mx, e);
    }
    #pragma unroll
    for (int off = 32; off; off >>= 1) mx = fmaxf(mx, __shfl_xor(mx, off));
    float m = (hi > lo) ? mx : 0.0f;   // ref: e_max -> 0 when not finite

    float sum = 0.0f;
    for (int n = lo + t; n < hi; n += 64) sum += expf(e_buf[n] - m);
    #pragma unroll
    for (int off = 32; off; off >>= 1) sum += __shfl_xor(sum, off);
    float denom = fmaxf(sum, 1e-16f);

    float r[DIM];
    #pragma unroll
    for (int d = 0; d < DIM; ++d) r[d] = 0.0f;
    for (int n = lo + t; n < hi; n += 64) {
        float a = expf(e_buf[n] - m) / denom;
        const float* xr = x + (size_t)n * DIM;
        #pragma unroll
        for (int d = 0; d < DIM; ++d) r[d] = fmaf(a, xr[d], r[d]);
    }
    #pragma unroll
    for (int d = 0; d < DIM; ++d) {
        #pragma unroll
        for (int off = 32; off; off >>= 1) r[d] += __shfl_xor(r[d], off);
    }
    if (t < DIM) {
        q_star[(size_t)g * 48 + t] = qs[t];       // q part
        q_star[(size_t)g * 48 + DIM + t] = r[t];  // r part
    }
}

// ---------- head: out = relu(q_star@w_fc2+b)@w_fc3+b ----------
__global__ void head_kernel(
    const float* __restrict__ q_star, const float* __restrict__ w2,
    const float* __restrict__ b2, const float* __restrict__ w3,
    const float* __restrict__ b3, float* __restrict__ out)
{
    int g = blockIdx.x * blockDim.x + threadIdx.x;
    if (g >= N_GRAPHS) return;
    const float* q = q_star + (size_t)g * 48;
    float z[8];
    #pragma unroll
    for (int k = 0; k < 8; ++k) {
        float a = b2[k];
        for (int j = 0; j < 48; ++j) a = fmaf(q[j], w2[j * 8 + k], a);
        z[k] = fmaxf(a, 0.0f);
    }
    #pragma unroll
    for (int c = 0; c < 2; ++c) {
        float a = b3[c];
        #pragma unroll
        for (int k = 0; k < 8; ++k) a = fmaf(z[k], w3[k * 2 + c], a);
        out[(size_t)g * 2 + c] = a;
    }
}

extern "C" void kernel_launch(void* const* d_in, const int* in_sizes, int n_in,
                              void* d_out, int out_size, void* d_ws, size_t ws_size,
                              hipStream_t stream) {
    const float* x      = (const float*)d_in[0];
    const float* ea     = (const float*)d_in[1];
    const float* w_e1   = (const float*)d_in[2];
    const float* b_e1   = (const float*)d_in[3];
    const float* w_e2   = (const float*)d_in[4];
    const float* b_e2   = (const float*)d_in[5];
    const float* root   = (const float*)d_in[6];
    const float* bias_c = (const float*)d_in[7];
    const float* w_ih   = (const float*)d_in[8];
    const float* w_hh   = (const float*)d_in[9];
    const float* b_ih   = (const float*)d_in[10];
    const float* b_hh   = (const float*)d_in[11];
    const float* w_fc2  = (const float*)d_in[12];
    const float* b_fc2  = (const float*)d_in[13];
    const float* w_fc3  = (const float*)d_in[14];
    const float* b_fc3  = (const float*)d_in[15];
    const int*   eidx   = (const int*)d_in[16];
    const int*   batch  = (const int*)d_in[17];
    const int* esrc = eidx;
    const int* edst = eidx + N_EDGES;
    float* out = (float*)d_out;

    // workspace layout (bytes)
    char* ws = (char*)d_ws;
    float* agg   = (float*)(ws);                  // 4,800,000
    int*   deg   = (int*)  (ws + 4800000);        //   200,000
    float* qstar = (float*)(ws + 5000000);        //   196,608
    float* h0    = (float*)(ws + 5196608);        // 4 x 98,304
    float* c0    = h0 + 24576;
    float* h1    = c0 + 24576;
    float* c1    = h1 + 24576;
    float* ebuf  = (float*)(ws + 5589824);        //   200,000
    float* x1    = (float*)(ws + 5789824);        // 4,800,000
    float* x2    = (float*)(ws + 10589824);       // 4,800,000
    unsigned short* w2s = (unsigned short*)(ws + 15389824);   // 147,456 B swizzled bf16 w2

    // zero: agg, deg, qstar, h0/c0/h1/c1
    hipMemsetAsync(ws, 0, 5589824, stream);

    deg_kernel<<<(N_EDGES + 255) / 256, 256, 0, stream>>>(edst, deg);
    w2s_kernel<<<(DD * EH + 255) / 256, 256, 0, stream>>>(w_e2, w2s);

    // layer 1 (fused edge-MLP + message + scatter; no W materialization)
    conv_kernel<<<N_EDGES / 64, 256, 0, stream>>>(x, ea, w_e1, b_e1, w2s, b_e2, esrc, edst, agg);
    combine_kernel<<<(N_NODES * DIM + 255) / 256, 256, 0, stream>>>(x, agg, deg, root, bias_c, x1, 1);

    // layer 2
    hipMemsetAsync(agg, 0, 4800000, stream);
    conv_kernel<<<N_EDGES / 64, 256, 0, stream>>>(x1, ea, w_e1, b_e1, w2s, b_e2, esrc, edst, agg);
    combine_kernel<<<(N_NODES * DIM + 255) / 256, 256, 0, stream>>>(x1, agg, deg, root, bias_c, x2, 0);

    // Set2Set: 3 iterations
    float *hA = h0, *cA = c0, *hB = h1, *cB = c1;
    for (int it = 0; it < 3; ++it) {
        lstm_kernel<<<(N_GRAPHS * DIM + 255) / 256, 256, 0, stream>>>(
            qstar, hA, cA, w_ih, w_hh, b_ih, b_hh, hB, cB);
        attn_kernel<<<N_GRAPHS, 64, 0, stream>>>(x2, batch, hB, qstar, ebuf);
        float* th = hA; hA = hB; hB = th;
        float* tc = cA; cA = cB; cB = tc;
    }

    head_kernel<<<(N_GRAPHS + 255) / 256, 256, 0, stream>>>(qstar, w_fc2, b_fc2, w_fc3, b_fc3, out);
}

// Round 4
// 451.097 us; speedup vs baseline: 1.3152x; 1.3152x over previous
//
#include <hip/hip_runtime.h>
#include <math.h>

#define N_NODES 50000
#define N_EDGES 200000
#define N_GRAPHS 1024
#define DIM 24
#define EF 8
#define EH 128
#define DD 576   // 24*24
#define SA 136   // LDS stride (bf16 elems) for A tile: 128 + 8 pad -> 2-way bank alias (free)
#define SC 104   // LDS stride (bf16 elems) for C tile: 96 + 8 pad

typedef __attribute__((ext_vector_type(8))) short short8;
typedef __attribute__((ext_vector_type(4))) float float4e;

// ---------- helpers ----------
static __device__ __forceinline__ unsigned short f2bf(float f) {
    union { float f; unsigned int u; } v; v.f = f;
    unsigned int u = v.u;
    u += ((u >> 16) & 1u) + 0x7FFFu;   // RNE
    return (unsigned short)(u >> 16);
}
static __device__ __forceinline__ float bf2f(unsigned short s) {
    union { unsigned int u; float f; } v; v.u = ((unsigned int)s) << 16;
    return v.f;
}
static __device__ __forceinline__ float sigm(float x) { return 1.0f / (1.0f + expf(-x)); }

// ---------- deg (in-degree per node) ----------
__global__ void deg_kernel(const int* __restrict__ dst, int* __restrict__ deg) {
    int i = blockIdx.x * blockDim.x + threadIdx.x;
    if (i < N_EDGES) atomicAdd(&deg[dst[i]], 1);
}

// ---------- w2 transpose + bf16: w2t[n][k] = bf16(w2[k][n]) ----------
__global__ __launch_bounds__(256) void w2t_kernel(const float* __restrict__ w2,
                                                  unsigned short* __restrict__ w2t) {
    int idx = blockIdx.x * 256 + threadIdx.x;   // idx = n*128 + k
    if (idx >= DD * EH) return;
    int n = idx >> 7, k = idx & 127;
    w2t[idx] = f2bf(w2[(size_t)k * DD + n]);
}

// ---------- fused edge MLP via MFMA ----------
// grid (6, 3125), block 256 (4 waves). Per block: 64 edges x 96 cols, K=128.
// RETILE vs rounds 0-2 (which used 288 cols/block, wave = 9 n-tiles = 36 B-loads):
// three rounds of evidence said the bottleneck is the per-wave chain of
// serialized L2 B-fragment loads (~300cyc each; compiler can't keep 36 frags
// live at any launch_bounds). Now wave = 2 m-tiles x 3 n-tiles -> only 12
// B-loads (48 VGPR) + acc 24 VGPR: small enough to preload for real, and
// occupancy stays ~3 waves/SIMD. Stage-A recompute x6 is ~16us aggregate VALU
// (sub-dominant). Expected floor: the 225MB W write stream.
__global__ __launch_bounds__(256) void gemm_w_kernel(
    const float* __restrict__ ea, const float* __restrict__ w1,
    const float* __restrict__ b1, const unsigned short* __restrict__ w2t,
    const float* __restrict__ b2, unsigned short* __restrict__ W)
{
    // Union buffer: stage-A tile (64 x SA) during GEMM, C tile (64 x SC) in epilogue.
    __shared__ unsigned short Tile[64 * SA];   // 17408 B -> LDS allows 9 blocks/CU

    const int t  = threadIdx.x;
    const int e0 = blockIdx.y * 64;
    const int n0 = blockIdx.x * 96;

    const int lane = t & 63;
    const int wave = t >> 6;
    const int l16  = lane & 15;          // A row (m) / B col (n) / C col
    const int quad = lane >> 4;          // k sub-block / C row group
    const int mw   = (wave & 1) * 2;     // m-tile pair: tiles mw, mw+1
    const int ng   = (wave >> 1) * 3;    // n-tile group (3 tiles of 16)

    // ---- issue all 12 B-fragment loads up front (L2-hot w2t) ----
    const unsigned short* Bb = w2t + (size_t)(n0 + ng * 16 + l16) * EH + quad * 8;
    short8 bfrag[4][3];
    #pragma unroll
    for (int ks = 0; ks < 4; ++ks)
        #pragma unroll
        for (int j = 0; j < 3; ++j)
            bfrag[ks][j] = *(const short8*)(Bb + (size_t)j * 16 * EH + ks * 32);

    // ---- acc init from bias ----
    float4e acc[2][3];
    #pragma unroll
    for (int j = 0; j < 3; ++j) {
        float bb = b2[n0 + (ng + j) * 16 + l16];
        float4e v = {bb, bb, bb, bb};
        acc[0][j] = v; acc[1][j] = v;
    }

    // ---- stage A: 64 edges x 128 hid; thread = (k-slice of 4) x (8 edges) ----
    {
        const int ks = t & 31;          // k = ks*4 .. ks*4+3
        const int eb = (t >> 5) * 8;    // 8 edges starting here
        float wv[EF][4];
        #pragma unroll
        for (int j = 0; j < EF; ++j) {
            float4 v = *(const float4*)(w1 + j * EH + ks * 4);
            wv[j][0] = v.x; wv[j][1] = v.y; wv[j][2] = v.z; wv[j][3] = v.w;
        }
        float4 bv = *(const float4*)(b1 + ks * 4);
        const float bvv[4] = {bv.x, bv.y, bv.z, bv.w};
        #pragma unroll
        for (int e = 0; e < 8; ++e) {
            const float* ear = ea + (size_t)(e0 + eb + e) * EF;
            float4 a0 = *(const float4*)ear;
            float4 a1 = *(const float4*)(ear + 4);
            const float av[EF] = {a0.x, a0.y, a0.z, a0.w, a1.x, a1.y, a1.z, a1.w};
            float r[4] = {bvv[0], bvv[1], bvv[2], bvv[3]};
            #pragma unroll
            for (int j = 0; j < EF; ++j)
                #pragma unroll
                for (int c = 0; c < 4; ++c)
                    r[c] = fmaf(av[j], wv[j][c], r[c]);
            ushort4 hq;
            hq.x = f2bf(fmaxf(r[0], 0.0f));
            hq.y = f2bf(fmaxf(r[1], 0.0f));
            hq.z = f2bf(fmaxf(r[2], 0.0f));
            hq.w = f2bf(fmaxf(r[3], 0.0f));
            *(ushort4*)&Tile[(eb + e) * SA + ks * 4] = hq;
        }
    }
    __syncthreads();

    // ---- A fragments: one batched set of LDS reads ----
    const unsigned short* A0 = Tile + (mw * 16 + l16) * SA + quad * 8;
    short8 afrag[4][2];
    #pragma unroll
    for (int ks = 0; ks < 4; ++ks) {
        afrag[ks][0] = *(const short8*)(A0 + ks * 32);
        afrag[ks][1] = *(const short8*)(A0 + 16 * SA + ks * 32);
    }

    // ---- MFMA: 24 matrix ops, all operands in registers ----
    #pragma unroll
    for (int ks = 0; ks < 4; ++ks) {
        #pragma unroll
        for (int j = 0; j < 3; ++j) {
            acc[0][j] = __builtin_amdgcn_mfma_f32_16x16x32_bf16(afrag[ks][0], bfrag[ks][j], acc[0][j], 0, 0, 0);
            acc[1][j] = __builtin_amdgcn_mfma_f32_16x16x32_bf16(afrag[ks][1], bfrag[ks][j], acc[1][j], 0, 0, 0);
        }
    }

    // ---- epilogue: acc -> LDS (C row = quad*4+reg, col = l16) -> wide stores ----
    __syncthreads();   // all A-tile reads done before Tile is reused as C-tile
    #pragma unroll
    for (int mm = 0; mm < 2; ++mm) {
        const int rbase = (mw + mm) * 16 + quad * 4;
        #pragma unroll
        for (int j = 0; j < 3; ++j) {
            const int cc = (ng + j) * 16 + l16;
            #pragma unroll
            for (int r = 0; r < 4; ++r)
                Tile[(rbase + r) * SC + cc] = f2bf(acc[mm][j][r]);
        }
    }
    __syncthreads();

    // 64 rows x 96 cols bf16 = 768 uint4; 256 threads x 3 iters, coalesced.
    #pragma unroll
    for (int k = 0; k < 3; ++k) {
        const int i = t + k * 256;
        const int row = i / 12;
        const int c   = i - row * 12;   // uint4 index within the 96-col slice
        *(uint4*)(W + (size_t)(e0 + row) * DD + n0 + c * 8) =
            *(const uint4*)&Tile[row * SC + c * 8];
    }
}

// ---------- messages: msg[e][o] = sum_i x[src[e]][i] * W[e][i*24+o]; scatter to agg ----------
// block 384 = 16 edges x 24 lanes; grid 12500
__global__ __launch_bounds__(384) void msg_kernel(
    const float* __restrict__ x, const unsigned short* __restrict__ W,
    const int* __restrict__ src, const int* __restrict__ dst,
    float* __restrict__ agg)
{
    __shared__ float xs[16][24];
    __shared__ unsigned short Ws[16][DD];
    const int e0 = blockIdx.x * 16;
    const int t = threadIdx.x;

    if (t < 96) {                    // 16 rows x 6 float4
        int el = t / 6, j4 = (t % 6) * 4;
        int s = src[e0 + el];
        *(float4*)&xs[el][j4] = *(const float4*)(x + (size_t)s * DIM + j4);
    }
    for (int idx = t; idx < 16 * 72; idx += 384) {   // 16 rows x 72 uint4 (8 bf16 each)
        int el = idx / 72, c = idx % 72;
        *(uint4*)&Ws[el][c * 8] = *(const uint4*)(W + (size_t)(e0 + el) * DD + c * 8);
    }
    __syncthreads();

    int el = t / DIM, o = t % DIM;
    float m = 0.0f;
    #pragma unroll
    for (int i = 0; i < DIM; ++i)
        m = fmaf(xs[el][i], bf2f(Ws[el][i * DIM + o]), m);
    atomicAdd(&agg[(size_t)dst[e0 + el] * DIM + o], m);
}

// ---------- combine: x_out = [relu](agg/max(deg,1) + x_in@root + bias) ----------
__global__ void combine_kernel(
    const float* __restrict__ x_in, const float* __restrict__ agg,
    const int* __restrict__ deg, const float* __restrict__ root,
    const float* __restrict__ bias, float* __restrict__ x_out, int do_relu)
{
    int t = blockIdx.x * blockDim.x + threadIdx.x;
    if (t >= N_NODES * DIM) return;
    int v = t / DIM, o = t % DIM;
    int dg = deg[v];
    float d = dg > 0 ? (float)dg : 1.0f;
    float a = agg[t] / d + bias[o];
    const float* xr = x_in + (size_t)v * DIM;
    #pragma unroll
    for (int i = 0; i < DIM; ++i) a = fmaf(xr[i], root[i * DIM + o], a);
    x_out[t] = do_relu ? fmaxf(a, 0.0f) : a;
}

// ---------- Set2Set LSTM step: one thread per (graph, d) ----------
__global__ void lstm_kernel(
    const float* __restrict__ q_star, const float* __restrict__ h_in,
    const float* __restrict__ c_in, const float* __restrict__ w_ih,
    const float* __restrict__ w_hh, const float* __restrict__ b_ih,
    const float* __restrict__ b_hh, float* __restrict__ h_out,
    float* __restrict__ c_out)
{
    int t = blockIdx.x * blockDim.x + threadIdx.x;
    if (t >= N_GRAPHS * DIM) return;
    int g = t / DIM, d = t % DIM;
    const float* qs = q_star + (size_t)g * 48;
    const float* hv = h_in + (size_t)g * DIM;
    float gate[4];
    #pragma unroll
    for (int r4 = 0; r4 < 4; ++r4) {
        int r = r4 * DIM + d;
        float a = b_ih[r] + b_hh[r];
        const float* wi = w_ih + (size_t)r * 48;
        const float* wh = w_hh + (size_t)r * DIM;
        for (int j = 0; j < 48; ++j) a = fmaf(qs[j], wi[j], a);
        #pragma unroll
        for (int j = 0; j < DIM; ++j) a = fmaf(hv[j], wh[j], a);
        gate[r4] = a;
    }
    float c = sigm(gate[1]) * c_in[t] + sigm(gate[0]) * tanhf(gate[2]);
    h_out[t] = sigm(gate[3]) * tanhf(c);
    c_out[t] = c;
}

// ---------- per-graph attention + readout (batch sorted -> binary search) ----------
__global__ __launch_bounds__(64) void attn_kernel(
    const float* __restrict__ x, const int* __restrict__ batch,
    const float* __restrict__ h, float* __restrict__ q_star,
    float* __restrict__ e_buf)
{
    const int g = blockIdx.x;
    const int t = threadIdx.x;
    __shared__ int s_lo, s_hi;
    __shared__ float qs[DIM];
    if (t == 0) {
        int lo = 0, hi = N_NODES;
        while (lo < hi) { int m = (lo + hi) >> 1; if (batch[m] < g) lo = m + 1; else hi = m; }
        s_lo = lo;
        int lo2 = lo; hi = N_NODES;
        while (lo2 < hi) { int m = (lo2 + hi) >> 1; if (batch[m] <= g) lo2 = m + 1; else hi = m; }
        s_hi = lo2;
    }
    if (t < DIM) qs[t] = h[(size_t)g * DIM + t];
    __syncthreads();
    const int lo = s_lo, hi = s_hi;

    float mx = -INFINITY;
    for (int n = lo + t; n < hi; n += 64) {
        const float* xr = x + (size_t)n * DIM;
        float e = 0.0f;
        #pragma unroll
        for (int d = 0; d < DIM; ++d) e = fmaf(xr[d], qs[d], e);
        e_buf[n] = e;
        mx = fmaxf(mx, e);
    }
    #pragma unroll
    for (int off = 32; off; off >>= 1) mx = fmaxf(mx, __shfl_xor(mx, off));
    float m = (hi > lo) ? mx : 0.0f;   // ref: e_max -> 0 when not finite

    float sum = 0.0f;
    for (int n = lo + t; n < hi; n += 64) sum += expf(e_buf[n] - m);
    #pragma unroll
    for (int off = 32; off; off >>= 1) sum += __shfl_xor(sum, off);
    float denom = fmaxf(sum, 1e-16f);

    float r[DIM];
    #pragma unroll
    for (int d = 0; d < DIM; ++d) r[d] = 0.0f;
    for (int n = lo + t; n < hi; n += 64) {
        float a = expf(e_buf[n] - m) / denom;
        const float* xr = x + (size_t)n * DIM;
        #pragma unroll
        for (int d = 0; d < DIM; ++d) r[d] = fmaf(a, xr[d], r[d]);
    }
    #pragma unroll
    for (int d = 0; d < DIM; ++d) {
        #pragma unroll
        for (int off = 32; off; off >>= 1) r[d] += __shfl_xor(r[d], off);
    }
    if (t < DIM) {
        q_star[(size_t)g * 48 + t] = qs[t];       // q part
        q_star[(size_t)g * 48 + DIM + t] = r[t];  // r part
    }
}

// ---------- head: out = relu(q_star@w_fc2+b)@w_fc3+b ----------
__global__ void head_kernel(
    const float* __restrict__ q_star, const float* __restrict__ w2,
    const float* __restrict__ b2, const float* __restrict__ w3,
    const float* __restrict__ b3, float* __restrict__ out)
{
    int g = blockIdx.x * blockDim.x + threadIdx.x;
    if (g >= N_GRAPHS) return;
    const float* q = q_star + (size_t)g * 48;
    float z[8];
    #pragma unroll
    for (int k = 0; k < 8; ++k) {
        float a = b2[k];
        for (int j = 0; j < 48; ++j) a = fmaf(q[j], w2[j * 8 + k], a);
        z[k] = fmaxf(a, 0.0f);
    }
    #pragma unroll
    for (int c = 0; c < 2; ++c) {
        float a = b3[c];
        #pragma unroll
        for (int k = 0; k < 8; ++k) a = fmaf(z[k], w3[k * 2 + c], a);
        out[(size_t)g * 2 + c] = a;
    }
}

extern "C" void kernel_launch(void* const* d_in, const int* in_sizes, int n_in,
                              void* d_out, int out_size, void* d_ws, size_t ws_size,
                              hipStream_t stream) {
    const float* x      = (const float*)d_in[0];
    const float* ea     = (const float*)d_in[1];
    const float* w_e1   = (const float*)d_in[2];
    const float* b_e1   = (const float*)d_in[3];
    const float* w_e2   = (const float*)d_in[4];
    const float* b_e2   = (const float*)d_in[5];
    const float* root   = (const float*)d_in[6];
    const float* bias_c = (const float*)d_in[7];
    const float* w_ih   = (const float*)d_in[8];
    const float* w_hh   = (const float*)d_in[9];
    const float* b_ih   = (const float*)d_in[10];
    const float* b_hh   = (const float*)d_in[11];
    const float* w_fc2  = (const float*)d_in[12];
    const float* b_fc2  = (const float*)d_in[13];
    const float* w_fc3  = (const float*)d_in[14];
    const float* b_fc3  = (const float*)d_in[15];
    const int*   eidx   = (const int*)d_in[16];
    const int*   batch  = (const int*)d_in[17];
    const int* esrc = eidx;
    const int* edst = eidx + N_EDGES;
    float* out = (float*)d_out;

    // workspace layout (bytes)
    char* ws = (char*)d_ws;
    float* agg   = (float*)(ws);                  // 4,800,000
    int*   deg   = (int*)  (ws + 4800000);        //   200,000
    float* qstar = (float*)(ws + 5000000);        //   196,608
    float* h0    = (float*)(ws + 5196608);        // 4 x 98,304
    float* c0    = h0 + 24576;
    float* h1    = c0 + 24576;
    float* c1    = h1 + 24576;
    float* ebuf  = (float*)(ws + 5589824);        //   200,000
    float* x1    = (float*)(ws + 5789824);        // 4,800,000
    float* x2    = (float*)(ws + 10589824);       // 4,800,000
    unsigned short* W   = (unsigned short*)(ws + 15389824);   // 230,400,000 bf16
    unsigned short* w2t = (unsigned short*)(ws + 245789824);  // 147,456 bf16

    // zero: agg, deg, qstar, h0/c0/h1/c1
    hipMemsetAsync(ws, 0, 5589824, stream);

    deg_kernel<<<(N_EDGES + 255) / 256, 256, 0, stream>>>(edst, deg);
    w2t_kernel<<<(DD * EH + 255) / 256, 256, 0, stream>>>(w_e2, w2t);
    gemm_w_kernel<<<dim3(6, N_EDGES / 64), 256, 0, stream>>>(ea, w_e1, b_e1, w2t, b_e2, W);

    // layer 1
    msg_kernel<<<N_EDGES / 16, 384, 0, stream>>>(x, W, esrc, edst, agg);
    combine_kernel<<<(N_NODES * DIM + 255) / 256, 256, 0, stream>>>(x, agg, deg, root, bias_c, x1, 1);

    // layer 2 (same edge weights W)
    hipMemsetAsync(agg, 0, 4800000, stream);
    msg_kernel<<<N_EDGES / 16, 384, 0, stream>>>(x1, W, esrc, edst, agg);
    combine_kernel<<<(N_NODES * DIM + 255) / 256, 256, 0, stream>>>(x1, agg, deg, root, bias_c, x2, 0);

    // Set2Set: 3 iterations
    float *hA = h0, *cA = c0, *hB = h1, *cB = c1;
    for (int it = 0; it < 3; ++it) {
        lstm_kernel<<<(N_GRAPHS * DIM + 255) / 256, 256, 0, stream>>>(
            qstar, hA, cA, w_ih, w_hh, b_ih, b_hh, hB, cB);
        attn_kernel<<<N_GRAPHS, 64, 0, stream>>>(x2, batch, hB, qstar, ebuf);
        float* th = hA; hA = hB; hB = th;
        float* tc = cA; cA = cB; cB = tc;
    }

    head_kernel<<<(N_GRAPHS + 255) / 256, 256, 0, stream>>>(qstar, w_fc2, b_fc2, w_fc3, b_fc3, out);
}

// Round 5
// 397.532 us; speedup vs baseline: 1.4925x; 1.1347x over previous
//
#include <hip/hip_runtime.h>
#include <math.h>

#define N_NODES 50000
#define N_EDGES 200000
#define N_GRAPHS 1024
#define DIM 24
#define EF 8
#define EH 128
#define DD 576   // 24*24

typedef __attribute__((ext_vector_type(8))) _Float16 f16x8;
typedef __attribute__((ext_vector_type(4))) _Float16 f16x4;
typedef __attribute__((ext_vector_type(2))) _Float16 f16x2;
typedef __attribute__((ext_vector_type(4))) float float4e;
typedef _Float16 f16;

// ---------- helpers ----------
static __device__ __forceinline__ float sigm(float x) { return 1.0f / (1.0f + expf(-x)); }

// ---------- deg (in-degree per node) ----------
__global__ void deg_kernel(const int* __restrict__ dst, int* __restrict__ deg) {
    int i = blockIdx.x * blockDim.x + threadIdx.x;
    if (i < N_EDGES) atomicAdd(&deg[dst[i]], 1);
}

// ---------- Bz: w2 (+b2) pre-swizzled f16 into exact MFMA b-fragment order ----------
// K-order: flat = i*128 + k  (i = x-feature 0..23, k = hidden 0..127), processed as
// 97 k-steps of 32: step p = si*24 + i covers k-window si*32..+32 of feature i
// (si = p/24? NO: p = si*24+i with si outer, i inner); step 96 = bias block
// (A = x, B = b2 reshaped). Layout: Bz[p 97][nt 2][lane 64][kk 8] f16, where
// lane = quad*16+l16, element = B[k32=quad*8+kk][n=nt*16+l16] (n>=24 -> 0).
// Total 97*2*64*8 = 99328 f16 = 198,656 B: L2-resident, shared by all blocks,
// every b-frag load is a contiguous 1KB wave read.
__global__ __launch_bounds__(256) void bz_kernel(const float* __restrict__ w2,
                                                 const float* __restrict__ b2,
                                                 f16* __restrict__ Bz) {
    int idx = blockIdx.x * 256 + threadIdx.x;
    if (idx >= 97 * 2 * 64 * 8) return;
    int kk = idx & 7, lane = (idx >> 3) & 63, nt = (idx >> 9) & 1, p = idx >> 10;
    int q = lane >> 4, l16 = lane & 15, n = nt * 16 + l16;
    float v = 0.0f;
    if (p < 96) {
        int si = p / 24, i = p % 24;
        int k = si * 32 + q * 8 + kk;
        if (n < 24) v = w2[(size_t)k * DD + i * 24 + n];
    } else {
        int i2 = q * 8 + kk;
        if (i2 < 24 && n < 24) v = b2[i2 * 24 + n];
    }
    Bz[idx] = (f16)v;
}

// ---------- fused NNConv: h-MLP + per-edge matvec as one z-GEMM, no W ----------
// grid 1563, block 512 (8 waves, 128 edges; tail guarded).
//   stage A: h = relu(ea@w1+b1) -> LDS f16 hs[kb 16][edge 128][kk 8]  (32 KB)
//   each wave: 16 edges (m-tile), K = 97 steps of 32, N = 24 (2 n-tiles).
//   A-frag formed in-register: z = h_slice * x_broadcast (4 v_pk_mul_f16);
//   h_slice hoisted: 4 LDS reads per wave TOTAL (reused across all 24 i).
//   b-frags: 2 contiguous 1KB loads/step from L2-hot Bz; barrier every 12
//   steps keeps the 8 waves lockstep so L1 (32KB) dedups their Bz streams.
//   Epilogue: 6 atomicAdd per thread (384/wave) into agg.
// Replaces gemm_w (179us) + 2x msg (~220us): no 225MB W write, no 450MB W read.
__global__ __launch_bounds__(512, 4) void conv_kernel(
    const float* __restrict__ x, const float* __restrict__ ea,
    const float* __restrict__ w1, const float* __restrict__ b1,
    const f16* __restrict__ Bz,
    const int* __restrict__ src, const int* __restrict__ dst,
    float* __restrict__ agg)
{
    __shared__ f16 hs[16384];   // [kb 16][edge 128][kk 8] = 32,768 B -> 4 blocks/CU

    const int t  = threadIdx.x;
    const int e0 = blockIdx.x * 128;

    // ---- stage A: h = relu(ea@w1+b1) -> hs ----
    {
        const int s5 = t & 31;           // k-slice: k = s5*4 .. s5*4+3
        const int eb = (t >> 5) * 8;     // 8 edges starting here
        const int kb = s5 >> 1, kk0 = (s5 & 1) * 4;
        float wv[EF][4];
        #pragma unroll
        for (int j = 0; j < EF; ++j) {
            float4 v = *(const float4*)(w1 + j * EH + s5 * 4);
            wv[j][0] = v.x; wv[j][1] = v.y; wv[j][2] = v.z; wv[j][3] = v.w;
        }
        float4 bv = *(const float4*)(b1 + s5 * 4);
        const float bvv[4] = {bv.x, bv.y, bv.z, bv.w};
        #pragma unroll
        for (int e = 0; e < 8; ++e) {
            int eg = e0 + eb + e; if (eg >= N_EDGES) eg = N_EDGES - 1;  // clamp tail
            const float* ear = ea + (size_t)eg * EF;
            float4 a0 = *(const float4*)ear;
            float4 a1 = *(const float4*)(ear + 4);
            const float av[EF] = {a0.x, a0.y, a0.z, a0.w, a1.x, a1.y, a1.z, a1.w};
            float r[4] = {bvv[0], bvv[1], bvv[2], bvv[3]};
            #pragma unroll
            for (int j = 0; j < EF; ++j)
                #pragma unroll
                for (int c = 0; c < 4; ++c)
                    r[c] = fmaf(av[j], wv[j][c], r[c]);
            f16x4 hq = { (f16)fmaxf(r[0], 0.0f), (f16)fmaxf(r[1], 0.0f),
                         (f16)fmaxf(r[2], 0.0f), (f16)fmaxf(r[3], 0.0f) };
            *(f16x4*)&hs[((kb * 128) + (eb + e)) * 8 + kk0] = hq;
        }
    }

    const int lane = t & 63;
    const int wave = t >> 6;         // wave owns edges e0+wave*16 .. +16
    const int l16  = lane & 15;      // A row (edge) / B col / C col
    const int quad = lane >> 4;      // k sub-block / C row group

    // ---- x[src[e]] row -> registers (f16); 4 quads duplicate -> L1 broadcast ----
    f16x2 x2v[12];
    {
        int eg = e0 + wave * 16 + l16; if (eg >= N_EDGES) eg = N_EDGES - 1;
        const float* xr = x + (size_t)src[eg] * DIM;
        #pragma unroll
        for (int j4 = 0; j4 < 6; ++j4) {
            float4 v = *(const float4*)(xr + j4 * 4);
            x2v[j4 * 2]     = (f16x2){(f16)v.x, (f16)v.y};
            x2v[j4 * 2 + 1] = (f16x2){(f16)v.z, (f16)v.w};
        }
    }

    __syncthreads();

    const f16x8* bz = (const f16x8*)Bz + lane;
    const f16x8* hv = (const f16x8*)hs;
    float4e acc0 = {0.f, 0.f, 0.f, 0.f}, acc1 = {0.f, 0.f, 0.f, 0.f};

    #pragma unroll
    for (int si = 0; si < 4; ++si) {
        union { f16x8 v; f16x2 p[4]; } hu;
        hu.v = hv[(si * 4 + quad) * 128 + wave * 16 + l16];   // h[e][si*32+quad*8 ..+8]
        #pragma unroll
        for (int i = 0; i < 24; ++i) {
            const int p = si * 24 + i;
            f16 xe = (i & 1) ? x2v[i >> 1][1] : x2v[i >> 1][0];   // compile-time idx
            f16x2 xi2 = {xe, xe};
            union { f16x8 v; f16x2 p[4]; } au;
            #pragma unroll
            for (int j = 0; j < 4; ++j) au.p[j] = hu.p[j] * xi2;  // v_pk_mul_f16
            f16x8 b0 = bz[p * 128];
            f16x8 b1 = bz[p * 128 + 64];
            acc0 = __builtin_amdgcn_mfma_f32_16x16x32_f16(au.v, b0, acc0, 0, 0, 0);
            acc1 = __builtin_amdgcn_mfma_f32_16x16x32_f16(au.v, b1, acc1, 0, 0, 0);
            if ((p % 12) == 11) __syncthreads();   // lockstep waves -> L1 dedups Bz
        }
    }
    // ---- bias step (p = 96): A = x row slices, B = b2 reshaped ----
    {
        union { f16x8 v; f16x2 p[4]; } au;
        if (quad == 0)      { au.p[0]=x2v[0]; au.p[1]=x2v[1]; au.p[2]=x2v[2];  au.p[3]=x2v[3];  }
        else if (quad == 1) { au.p[0]=x2v[4]; au.p[1]=x2v[5]; au.p[2]=x2v[6];  au.p[3]=x2v[7];  }
        else if (quad == 2) { au.p[0]=x2v[8]; au.p[1]=x2v[9]; au.p[2]=x2v[10]; au.p[3]=x2v[11]; }
        else { f16x2 z = {(f16)0.f, (f16)0.f}; au.p[0]=z; au.p[1]=z; au.p[2]=z; au.p[3]=z; }
        f16x8 b0 = bz[96 * 128];
        f16x8 b1 = bz[96 * 128 + 64];
        acc0 = __builtin_amdgcn_mfma_f32_16x16x32_f16(au.v, b0, acc0, 0, 0, 0);
        acc1 = __builtin_amdgcn_mfma_f32_16x16x32_f16(au.v, b1, acc1, 0, 0, 0);
    }

    // ---- scatter: C row = quad*4+r (edge), col = l16 (+16) = o ----
    #pragma unroll
    for (int r = 0; r < 4; ++r) {
        int eg = e0 + wave * 16 + quad * 4 + r;
        if (eg < N_EDGES) {
            int d = dst[eg];
            atomicAdd(&agg[(size_t)d * DIM + l16], acc0[r]);
            if (l16 < 8)
                atomicAdd(&agg[(size_t)d * DIM + 16 + l16], acc1[r]);
        }
    }
}

// ---------- combine: x_out = [relu](agg/max(deg,1) + x_in@root + bias) ----------
__global__ void combine_kernel(
    const float* __restrict__ x_in, const float* __restrict__ agg,
    const int* __restrict__ deg, const float* __restrict__ root,
    const float* __restrict__ bias, float* __restrict__ x_out, int do_relu)
{
    int t = blockIdx.x * blockDim.x + threadIdx.x;
    if (t >= N_NODES * DIM) return;
    int v = t / DIM, o = t % DIM;
    int dg = deg[v];
    float d = dg > 0 ? (float)dg : 1.0f;
    float a = agg[t] / d + bias[o];
    const float* xr = x_in + (size_t)v * DIM;
    #pragma unroll
    for (int i = 0; i < DIM; ++i) a = fmaf(xr[i], root[i * DIM + o], a);
    x_out[t] = do_relu ? fmaxf(a, 0.0f) : a;
}

// ---------- Set2Set LSTM step: one thread per (graph, d) ----------
__global__ void lstm_kernel(
    const float* __restrict__ q_star, const float* __restrict__ h_in,
    const float* __restrict__ c_in, const float* __restrict__ w_ih,
    const float* __restrict__ w_hh, const float* __restrict__ b_ih,
    const float* __restrict__ b_hh, float* __restrict__ h_out,
    float* __restrict__ c_out)
{
    int t = blockIdx.x * blockDim.x + threadIdx.x;
    if (t >= N_GRAPHS * DIM) return;
    int g = t / DIM, d = t % DIM;
    const float* qs = q_star + (size_t)g * 48;
    const float* hv = h_in + (size_t)g * DIM;
    float gate[4];
    #pragma unroll
    for (int r4 = 0; r4 < 4; ++r4) {
        int r = r4 * DIM + d;
        float a = b_ih[r] + b_hh[r];
        const float* wi = w_ih + (size_t)r * 48;
        const float* wh = w_hh + (size_t)r * DIM;
        for (int j = 0; j < 48; ++j) a = fmaf(qs[j], wi[j], a);
        #pragma unroll
        for (int j = 0; j < DIM; ++j) a = fmaf(hv[j], wh[j], a);
        gate[r4] = a;
    }
    float c = sigm(gate[1]) * c_in[t] + sigm(gate[0]) * tanhf(gate[2]);
    h_out[t] = sigm(gate[3]) * tanhf(c);
    c_out[t] = c;
}

// ---------- per-graph attention + readout (batch sorted -> binary search) ----------
__global__ __launch_bounds__(64) void attn_kernel(
    const float* __restrict__ x, const int* __restrict__ batch,
    const float* __restrict__ h, float* __restrict__ q_star,
    float* __restrict__ e_buf)
{
    const int g = blockIdx.x;
    const int t = threadIdx.x;
    __shared__ int s_lo, s_hi;
    __shared__ float qs[DIM];
    if (t == 0) {
        int lo = 0, hi = N_NODES;
        while (lo < hi) { int m = (lo + hi) >> 1; if (batch[m] < g) lo = m + 1; else hi = m; }
        s_lo = lo;
        int lo2 = lo; hi = N_NODES;
        while (lo2 < hi) { int m = (lo2 + hi) >> 1; if (batch[m] <= g) lo2 = m + 1; else hi = m; }
        s_hi = lo2;
    }
    if (t < DIM) qs[t] = h[(size_t)g * DIM + t];
    __syncthreads();
    const int lo = s_lo, hi = s_hi;

    float mx = -INFINITY;
    for (int n = lo + t; n < hi; n += 64) {
        const float* xr = x + (size_t)n * DIM;
        float e = 0.0f;
        #pragma unroll
        for (int d = 0; d < DIM; ++d) e = fmaf(xr[d], qs[d], e);
        e_buf[n] = e;
        mx = fmaxf(mx, e);
    }
    #pragma unroll
    for (int off = 32; off; off >>= 1) mx = fmaxf(mx, __shfl_xor(mx, off));
    float m = (hi > lo) ? mx : 0.0f;   // ref: e_max -> 0 when not finite

    float sum = 0.0f;
    for (int n = lo + t; n < hi; n += 64) sum += expf(e_buf[n] - m);
    #pragma unroll
    for (int off = 32; off; off >>= 1) sum += __shfl_xor(sum, off);
    float denom = fmaxf(sum, 1e-16f);

    float r[DIM];
    #pragma unroll
    for (int d = 0; d < DIM; ++d) r[d] = 0.0f;
    for (int n = lo + t; n < hi; n += 64) {
        float a = expf(e_buf[n] - m) / denom;
        const float* xr = x + (size_t)n * DIM;
        #pragma unroll
        for (int d = 0; d < DIM; ++d) r[d] = fmaf(a, xr[d], r[d]);
    }
    #pragma unroll
    for (int d = 0; d < DIM; ++d) {
        #pragma unroll
        for (int off = 32; off; off >>= 1) r[d] += __shfl_xor(r[d], off);
    }
    if (t < DIM) {
        q_star[(size_t)g * 48 + t] = qs[t];       // q part
        q_star[(size_t)g * 48 + DIM + t] = r[t];  // r part
    }
}

// ---------- head: out = relu(q_star@w_fc2+b)@w_fc3+b ----------
__global__ void head_kernel(
    const float* __restrict__ q_star, const float* __restrict__ w2,
    const float* __restrict__ b2, const float* __restrict__ w3,
    const float* __restrict__ b3, float* __restrict__ out)
{
    int g = blockIdx.x * blockDim.x + threadIdx.x;
    if (g >= N_GRAPHS) return;
    const float* q = q_star + (size_t)g * 48;
    float z[8];
    #pragma unroll
    for (int k = 0; k < 8; ++k) {
        float a = b2[k];
        for (int j = 0; j < 48; ++j) a = fmaf(q[j], w2[j * 8 + k], a);
        z[k] = fmaxf(a, 0.0f);
    }
    #pragma unroll
    for (int c = 0; c < 2; ++c) {
        float a = b3[c];
        #pragma unroll
        for (int k = 0; k < 8; ++k) a = fmaf(z[k], w3[k * 2 + c], a);
        out[(size_t)g * 2 + c] = a;
    }
}

extern "C" void kernel_launch(void* const* d_in, const int* in_sizes, int n_in,
                              void* d_out, int out_size, void* d_ws, size_t ws_size,
                              hipStream_t stream) {
    const float* x      = (const float*)d_in[0];
    const float* ea     = (const float*)d_in[1];
    const float* w_e1   = (const float*)d_in[2];
    const float* b_e1   = (const float*)d_in[3];
    const float* w_e2   = (const float*)d_in[4];
    const float* b_e2   = (const float*)d_in[5];
    const float* root   = (const float*)d_in[6];
    const float* bias_c = (const float*)d_in[7];
    const float* w_ih   = (const float*)d_in[8];
    const float* w_hh   = (const float*)d_in[9];
    const float* b_ih   = (const float*)d_in[10];
    const float* b_hh   = (const float*)d_in[11];
    const float* w_fc2  = (const float*)d_in[12];
    const float* b_fc2  = (const float*)d_in[13];
    const float* w_fc3  = (const float*)d_in[14];
    const float* b_fc3  = (const float*)d_in[15];
    const int*   eidx   = (const int*)d_in[16];
    const int*   batch  = (const int*)d_in[17];
    const int* esrc = eidx;
    const int* edst = eidx + N_EDGES;
    float* out = (float*)d_out;

    // workspace layout (bytes)
    char* ws = (char*)d_ws;
    float* agg   = (float*)(ws);                  // 4,800,000
    int*   deg   = (int*)  (ws + 4800000);        //   200,000
    float* qstar = (float*)(ws + 5000000);        //   196,608
    float* h0    = (float*)(ws + 5196608);        // 4 x 98,304
    float* c0    = h0 + 24576;
    float* h1    = c0 + 24576;
    float* c1    = h1 + 24576;
    float* ebuf  = (float*)(ws + 5589824);        //   200,000
    float* x1    = (float*)(ws + 5789824);        // 4,800,000
    float* x2    = (float*)(ws + 10589824);       // 4,800,000
    f16*   Bz    = (f16*)  (ws + 15389824);       //   198,656 swizzled f16 w2+b2

    // zero: agg, deg, qstar, h0/c0/h1/c1
    hipMemsetAsync(ws, 0, 5589824, stream);

    deg_kernel<<<(N_EDGES + 255) / 256, 256, 0, stream>>>(edst, deg);
    bz_kernel<<<(97 * 2 * 64 * 8 + 255) / 256, 256, 0, stream>>>(w_e2, b_e2, Bz);

    // layer 1 (fused edge-MLP + message + scatter; no W materialization)
    conv_kernel<<<(N_EDGES + 127) / 128, 512, 0, stream>>>(x, ea, w_e1, b_e1, Bz, esrc, edst, agg);
    combine_kernel<<<(N_NODES * DIM + 255) / 256, 256, 0, stream>>>(x, agg, deg, root, bias_c, x1, 1);

    // layer 2
    hipMemsetAsync(agg, 0, 4800000, stream);
    conv_kernel<<<(N_EDGES + 127) / 128, 512, 0, stream>>>(x1, ea, w_e1, b_e1, Bz, esrc, edst, agg);
    combine_kernel<<<(N_NODES * DIM + 255) / 256, 256, 0, stream>>>(x1, agg, deg, root, bias_c, x2, 0);

    // Set2Set: 3 iterations
    float *hA = h0, *cA = c0, *hB = h1, *cB = c1;
    for (int it = 0; it < 3; ++it) {
        lstm_kernel<<<(N_GRAPHS * DIM + 255) / 256, 256, 0, stream>>>(
            qstar, hA, cA, w_ih, w_hh, b_ih, b_hh, hB, cB);
        attn_kernel<<<N_GRAPHS, 64, 0, stream>>>(x2, batch, hB, qstar, ebuf);
        float* th = hA; hA = hB; hB = th;
        float* tc = cA; cA = cB; cB = tc;
    }

    head_kernel<<<(N_GRAPHS + 255) / 256, 256, 0, stream>>>(qstar, w_fc2, b_fc2, w_fc3, b_fc3, out);
}

// Round 6
// 330.179 us; speedup vs baseline: 1.7969x; 1.2040x over previous
//
#include <hip/hip_runtime.h>
#include <math.h>

#define N_NODES 50000
#define N_EDGES 200000
#define N_GRAPHS 1024
#define DIM 24
#define EF 8
#define EH 128
#define DD 576   // 24*24
#define HSTR 136 // hs row stride in f16: 128 + 8 pad (breaks stage-A write conflicts)

typedef __attribute__((ext_vector_type(8))) _Float16 f16x8;
typedef __attribute__((ext_vector_type(4))) _Float16 f16x4;
typedef __attribute__((ext_vector_type(2))) _Float16 f16x2;
typedef __attribute__((ext_vector_type(4))) float float4e;
typedef _Float16 f16;

// ---------- helpers ----------
static __device__ __forceinline__ float sigm(float x) { return 1.0f / (1.0f + expf(-x)); }

// ---------- deg (in-degree per node) ----------
__global__ void deg_kernel(const int* __restrict__ dst, int* __restrict__ deg) {
    int i = blockIdx.x * blockDim.x + threadIdx.x;
    if (i < N_EDGES) atomicAdd(&deg[dst[i]], 1);
}

// ---------- Bz: w2 (+b2) pre-swizzled f16 into exact MFMA b-fragment order ----------
// 97 k-steps of 32: step p = si*24+i covers k-window si*32..+32 of x-feature i;
// step 96 = bias block (A = x, B = b2 reshaped).
// Layout: Bz[p 97][nt 2][lane 64][kk 8] f16; lane = quad*16+l16,
// element = B[k32=quad*8+kk][n=nt*16+l16] (n>=24 -> 0). 198,656 B, L2-resident.
__global__ __launch_bounds__(256) void bz_kernel(const float* __restrict__ w2,
                                                 const float* __restrict__ b2,
                                                 f16* __restrict__ Bz) {
    int idx = blockIdx.x * 256 + threadIdx.x;
    if (idx >= 97 * 2 * 64 * 8) return;
    int kk = idx & 7, lane = (idx >> 3) & 63, nt = (idx >> 9) & 1, p = idx >> 10;
    int q = lane >> 4, l16 = lane & 15, n = nt * 16 + l16;
    float v = 0.0f;
    if (p < 96) {
        int si = p / 24, i = p % 24;
        int k = si * 32 + q * 8 + kk;
        if (n < 24) v = w2[(size_t)k * DD + i * 24 + n];
    } else {
        int i2 = q * 8 + kk;
        if (i2 < 24 && n < 24) v = b2[i2 * 24 + n];
    }
    Bz[idx] = (f16)v;
}

// ---------- fused NNConv: h-MLP + per-edge matvec as one z-GEMM, no W ----------
// grid 1563, block 256 (4 waves, 128 edges).  Round-6 changes vs round 5:
//  * wave owns 32 edges (2 m-tiles) -> 4 MFMA per b-frag pair: 2x arith
//    intensity, 4 independent acc chains (was 2), half the Bz traffic.
//  * depth-2 b-frag double-buffer with compile-time indices, initial loads
//    issued before the barrier -> loads 2 steps ahead of use (~80+ cyc cover).
//    r5's VGPR=32 showed the compiler serialized every b-load; launch_bounds
//    (256,4) = 128-VGPR budget fits the ~110-reg working set for real.
//  * hs relayout [edge 128][k 128 +8 pad]: stage-A writes 4-way instead of
//    32-way bank-conflicted (r5: 2.8M conflict cycles).
__global__ __launch_bounds__(256, 4) void conv_kernel(
    const float* __restrict__ x, const float* __restrict__ ea,
    const float* __restrict__ w1, const float* __restrict__ b1,
    const f16* __restrict__ Bz,
    const int* __restrict__ src, const int* __restrict__ dst,
    float* __restrict__ agg)
{
    __shared__ f16 hs[128 * HSTR];   // 34,816 B -> 4 blocks/CU

    const int t  = threadIdx.x;
    const int e0 = blockIdx.x * 128;

    const int lane = t & 63;
    const int wave = t >> 6;             // wave owns edges e0+wave*32 .. +32
    const int l16  = lane & 15;          // A row (edge) / B col / C col
    const int quad = lane >> 4;          // k sub-block / C row group
    const int ebase = e0 + wave * 32;

    // ---- x rows for both m-tiles -> f16 registers (issued first; L1 dedups) ----
    f16x2 xa[12], xb[12];
    {
        int ega = ebase + l16;      if (ega >= N_EDGES) ega = N_EDGES - 1;
        int egb = ebase + 16 + l16; if (egb >= N_EDGES) egb = N_EDGES - 1;
        const float* xra = x + (size_t)src[ega] * DIM;
        const float* xrb = x + (size_t)src[egb] * DIM;
        #pragma unroll
        for (int j4 = 0; j4 < 6; ++j4) {
            float4 va = *(const float4*)(xra + j4 * 4);
            float4 vb = *(const float4*)(xrb + j4 * 4);
            xa[j4 * 2]     = (f16x2){(f16)va.x, (f16)va.y};
            xa[j4 * 2 + 1] = (f16x2){(f16)va.z, (f16)va.w};
            xb[j4 * 2]     = (f16x2){(f16)vb.x, (f16)vb.y};
            xb[j4 * 2 + 1] = (f16x2){(f16)vb.z, (f16)vb.w};
        }
    }

    // ---- stage A: h = relu(ea@w1+b1) -> hs[edge][k]; thread = 4-k-slice x 16 edges ----
    {
        const int s5 = t & 31;           // k = s5*4 .. s5*4+3
        const int eb = (t >> 5) * 16;    // 16 edges starting here
        float wv[EF][4];
        #pragma unroll
        for (int j = 0; j < EF; ++j) {
            float4 v = *(const float4*)(w1 + j * EH + s5 * 4);
            wv[j][0] = v.x; wv[j][1] = v.y; wv[j][2] = v.z; wv[j][3] = v.w;
        }
        float4 bv = *(const float4*)(b1 + s5 * 4);
        const float bvv[4] = {bv.x, bv.y, bv.z, bv.w};
        #pragma unroll
        for (int e = 0; e < 16; ++e) {
            int eg = e0 + eb + e; if (eg >= N_EDGES) eg = N_EDGES - 1;  // clamp tail
            const float* ear = ea + (size_t)eg * EF;
            float4 a0 = *(const float4*)ear;
            float4 a1 = *(const float4*)(ear + 4);
            const float av[EF] = {a0.x, a0.y, a0.z, a0.w, a1.x, a1.y, a1.z, a1.w};
            float r[4] = {bvv[0], bvv[1], bvv[2], bvv[3]};
            #pragma unroll
            for (int j = 0; j < EF; ++j)
                #pragma unroll
                for (int c = 0; c < 4; ++c)
                    r[c] = fmaf(av[j], wv[j][c], r[c]);
            f16x4 hq = { (f16)fmaxf(r[0], 0.0f), (f16)fmaxf(r[1], 0.0f),
                         (f16)fmaxf(r[2], 0.0f), (f16)fmaxf(r[3], 0.0f) };
            *(f16x4*)&hs[(eb + e) * HSTR + s5 * 4] = hq;
        }
    }

    // ---- prime depth-2 b-frag pipeline (independent of LDS; overlaps barrier) ----
    const f16x8* bz = (const f16x8*)Bz + lane;
    f16x8 pb0[2], pb1[2];
    pb0[0] = bz[0];   pb1[0] = bz[64];
    pb0[1] = bz[128]; pb1[1] = bz[192];

    __syncthreads();

    float4e a00 = {0.f,0.f,0.f,0.f}, a01 = {0.f,0.f,0.f,0.f};
    float4e a10 = {0.f,0.f,0.f,0.f}, a11 = {0.f,0.f,0.f,0.f};

    #pragma unroll
    for (int si = 0; si < 4; ++si) {
        union { f16x8 v; f16x2 p[4]; } h0u, h1u;
        h0u.v = *(const f16x8*)&hs[(wave * 32 + l16) * HSTR + si * 32 + quad * 8];
        h1u.v = *(const f16x8*)&hs[(wave * 32 + 16 + l16) * HSTR + si * 32 + quad * 8];
        #pragma unroll
        for (int i = 0; i < 24; ++i) {
            const int p = si * 24 + i;          // compile-time
            f16x8 b0 = pb0[p & 1], b1v = pb1[p & 1];
            if (p + 2 <= 96) {                  // prefetch 2 steps ahead into freed slot
                pb0[p & 1] = bz[(p + 2) * 128];
                pb1[p & 1] = bz[(p + 2) * 128 + 64];
            }
            f16 xea = (i & 1) ? xa[i >> 1][1] : xa[i >> 1][0];
            f16 xeb = (i & 1) ? xb[i >> 1][1] : xb[i >> 1][0];
            f16x2 xa2 = {xea, xea}, xb2 = {xeb, xeb};
            union { f16x8 v; f16x2 p[4]; } a0u, a1u;
            #pragma unroll
            for (int j = 0; j < 4; ++j) {
                a0u.p[j] = h0u.p[j] * xa2;      // v_pk_mul_f16
                a1u.p[j] = h1u.p[j] * xb2;
            }
            a00 = __builtin_amdgcn_mfma_f32_16x16x32_f16(a0u.v, b0,  a00, 0, 0, 0);
            a10 = __builtin_amdgcn_mfma_f32_16x16x32_f16(a1u.v, b0,  a10, 0, 0, 0);
            a01 = __builtin_amdgcn_mfma_f32_16x16x32_f16(a0u.v, b1v, a01, 0, 0, 0);
            a11 = __builtin_amdgcn_mfma_f32_16x16x32_f16(a1u.v, b1v, a11, 0, 0, 0);
            if ((p % 12) == 11) __syncthreads();   // lockstep waves -> L1 dedups Bz
        }
    }

    // ---- bias step (p = 96): A = x row slices, B = b2 reshaped; frags in slot 0 ----
    {
        union { f16x8 v; f16x2 p[4]; } a0u, a1u;
        f16x2 z2 = {(f16)0.f, (f16)0.f};
        if (quad == 0)      { a0u.p[0]=xa[0]; a0u.p[1]=xa[1]; a0u.p[2]=xa[2];  a0u.p[3]=xa[3];
                              a1u.p[0]=xb[0]; a1u.p[1]=xb[1]; a1u.p[2]=xb[2];  a1u.p[3]=xb[3];  }
        else if (quad == 1) { a0u.p[0]=xa[4]; a0u.p[1]=xa[5]; a0u.p[2]=xa[6];  a0u.p[3]=xa[7];
                              a1u.p[0]=xb[4]; a1u.p[1]=xb[5]; a1u.p[2]=xb[6];  a1u.p[3]=xb[7];  }
        else if (quad == 2) { a0u.p[0]=xa[8]; a0u.p[1]=xa[9]; a0u.p[2]=xa[10]; a0u.p[3]=xa[11];
                              a1u.p[0]=xb[8]; a1u.p[1]=xb[9]; a1u.p[2]=xb[10]; a1u.p[3]=xb[11]; }
        else                { a0u.p[0]=z2; a0u.p[1]=z2; a0u.p[2]=z2; a0u.p[3]=z2;
                              a1u.p[0]=z2; a1u.p[1]=z2; a1u.p[2]=z2; a1u.p[3]=z2; }
        a00 = __builtin_amdgcn_mfma_f32_16x16x32_f16(a0u.v, pb0[0], a00, 0, 0, 0);
        a10 = __builtin_amdgcn_mfma_f32_16x16x32_f16(a1u.v, pb0[0], a10, 0, 0, 0);
        a01 = __builtin_amdgcn_mfma_f32_16x16x32_f16(a0u.v, pb1[0], a01, 0, 0, 0);
        a11 = __builtin_amdgcn_mfma_f32_16x16x32_f16(a1u.v, pb1[0], a11, 0, 0, 0);
    }

    // ---- scatter: C row = quad*4+r (edge), col = l16 (+16) = o ----
    #pragma unroll
    for (int r = 0; r < 4; ++r) {
        int er = ebase + quad * 4 + r;
        if (er < N_EDGES) {
            int d = dst[er];
            atomicAdd(&agg[(size_t)d * DIM + l16], a00[r]);
            if (l16 < 8) atomicAdd(&agg[(size_t)d * DIM + 16 + l16], a01[r]);
        }
        int er2 = ebase + 16 + quad * 4 + r;
        if (er2 < N_EDGES) {
            int d = dst[er2];
            atomicAdd(&agg[(size_t)d * DIM + l16], a10[r]);
            if (l16 < 8) atomicAdd(&agg[(size_t)d * DIM + 16 + l16], a11[r]);
        }
    }
}

// ---------- combine: x_out = [relu](agg/max(deg,1) + x_in@root + bias) ----------
__global__ void combine_kernel(
    const float* __restrict__ x_in, const float* __restrict__ agg,
    const int* __restrict__ deg, const float* __restrict__ root,
    const float* __restrict__ bias, float* __restrict__ x_out, int do_relu)
{
    int t = blockIdx.x * blockDim.x + threadIdx.x;
    if (t >= N_NODES * DIM) return;
    int v = t / DIM, o = t % DIM;
    int dg = deg[v];
    float d = dg > 0 ? (float)dg : 1.0f;
    float a = agg[t] / d + bias[o];
    const float* xr = x_in + (size_t)v * DIM;
    #pragma unroll
    for (int i = 0; i < DIM; ++i) a = fmaf(xr[i], root[i * DIM + o], a);
    x_out[t] = do_relu ? fmaxf(a, 0.0f) : a;
}

// ---------- Set2Set LSTM step: one thread per (graph, d) ----------
__global__ void lstm_kernel(
    const float* __restrict__ q_star, const float* __restrict__ h_in,
    const float* __restrict__ c_in, const float* __restrict__ w_ih,
    const float* __restrict__ w_hh, const float* __restrict__ b_ih,
    const float* __restrict__ b_hh, float* __restrict__ h_out,
    float* __restrict__ c_out)
{
    int t = blockIdx.x * blockDim.x + threadIdx.x;
    if (t >= N_GRAPHS * DIM) return;
    int g = t / DIM, d = t % DIM;
    const float* qs = q_star + (size_t)g * 48;
    const float* hv = h_in + (size_t)g * DIM;
    float gate[4];
    #pragma unroll
    for (int r4 = 0; r4 < 4; ++r4) {
        int r = r4 * DIM + d;
        float a = b_ih[r] + b_hh[r];
        const float* wi = w_ih + (size_t)r * 48;
        const float* wh = w_hh + (size_t)r * DIM;
        for (int j = 0; j < 48; ++j) a = fmaf(qs[j], wi[j], a);
        #pragma unroll
        for (int j = 0; j < DIM; ++j) a = fmaf(hv[j], wh[j], a);
        gate[r4] = a;
    }
    float c = sigm(gate[1]) * c_in[t] + sigm(gate[0]) * tanhf(gate[2]);
    h_out[t] = sigm(gate[3]) * tanhf(c);
    c_out[t] = c;
}

// ---------- per-graph attention + readout (batch sorted -> binary search) ----------
__global__ __launch_bounds__(64) void attn_kernel(
    const float* __restrict__ x, const int* __restrict__ batch,
    const float* __restrict__ h, float* __restrict__ q_star,
    float* __restrict__ e_buf)
{
    const int g = blockIdx.x;
    const int t = threadIdx.x;
    __shared__ int s_lo, s_hi;
    __shared__ float qs[DIM];
    if (t == 0) {
        int lo = 0, hi = N_NODES;
        while (lo < hi) { int m = (lo + hi) >> 1; if (batch[m] < g) lo = m + 1; else hi = m; }
        s_lo = lo;
        int lo2 = lo; hi = N_NODES;
        while (lo2 < hi) { int m = (lo2 + hi) >> 1; if (batch[m] <= g) lo2 = m + 1; else hi = m; }
        s_hi = lo2;
    }
    if (t < DIM) qs[t] = h[(size_t)g * DIM + t];
    __syncthreads();
    const int lo = s_lo, hi = s_hi;

    float mx = -INFINITY;
    for (int n = lo + t; n < hi; n += 64) {
        const float* xr = x + (size_t)n * DIM;
        float e = 0.0f;
        #pragma unroll
        for (int d = 0; d < DIM; ++d) e = fmaf(xr[d], qs[d], e);
        e_buf[n] = e;
        mx = fmaxf(mx, e);
    }
    #pragma unroll
    for (int off = 32; off; off >>= 1) mx = fmaxf(mx, __shfl_xor(mx, off));
    float m = (hi > lo) ? mx : 0.0f;   // ref: e_max -> 0 when not finite

    float sum = 0.0f;
    for (int n = lo + t; n < hi; n += 64) sum += expf(e_buf[n] - m);
    #pragma unroll
    for (int off = 32; off; off >>= 1) sum += __shfl_xor(sum, off);
    float denom = fmaxf(sum, 1e-16f);

    float r[DIM];
    #pragma unroll
    for (int d = 0; d < DIM; ++d) r[d] = 0.0f;
    for (int n = lo + t; n < hi; n += 64) {
        float a = expf(e_buf[n] - m) / denom;
        const float* xr = x + (size_t)n * DIM;
        #pragma unroll
        for (int d = 0; d < DIM; ++d) r[d] = fmaf(a, xr[d], r[d]);
    }
    #pragma unroll
    for (int d = 0; d < DIM; ++d) {
        #pragma unroll
        for (int off = 32; off; off >>= 1) r[d] += __shfl_xor(r[d], off);
    }
    if (t < DIM) {
        q_star[(size_t)g * 48 + t] = qs[t];       // q part
        q_star[(size_t)g * 48 + DIM + t] = r[t];  // r part
    }
}

// ---------- head: out = relu(q_star@w_fc2+b)@w_fc3+b ----------
__global__ void head_kernel(
    const float* __restrict__ q_star, const float* __restrict__ w2,
    const float* __restrict__ b2, const float* __restrict__ w3,
    const float* __restrict__ b3, float* __restrict__ out)
{
    int g = blockIdx.x * blockDim.x + threadIdx.x;
    if (g >= N_GRAPHS) return;
    const float* q = q_star + (size_t)g * 48;
    float z[8];
    #pragma unroll
    for (int k = 0; k < 8; ++k) {
        float a = b2[k];
        for (int j = 0; j < 48; ++j) a = fmaf(q[j], w2[j * 8 + k], a);
        z[k] = fmaxf(a, 0.0f);
    }
    #pragma unroll
    for (int c = 0; c < 2; ++c) {
        float a = b3[c];
        #pragma unroll
        for (int k = 0; k < 8; ++k) a = fmaf(z[k], w3[k * 2 + c], a);
        out[(size_t)g * 2 + c] = a;
    }
}

extern "C" void kernel_launch(void* const* d_in, const int* in_sizes, int n_in,
                              void* d_out, int out_size, void* d_ws, size_t ws_size,
                              hipStream_t stream) {
    const float* x      = (const float*)d_in[0];
    const float* ea     = (const float*)d_in[1];
    const float* w_e1   = (const float*)d_in[2];
    const float* b_e1   = (const float*)d_in[3];
    const float* w_e2   = (const float*)d_in[4];
    const float* b_e2   = (const float*)d_in[5];
    const float* root   = (const float*)d_in[6];
    const float* bias_c = (const float*)d_in[7];
    const float* w_ih   = (const float*)d_in[8];
    const float* w_hh   = (const float*)d_in[9];
    const float* b_ih   = (const float*)d_in[10];
    const float* b_hh   = (const float*)d_in[11];
    const float* w_fc2  = (const float*)d_in[12];
    const float* b_fc2  = (const float*)d_in[13];
    const float* w_fc3  = (const float*)d_in[14];
    const float* b_fc3  = (const float*)d_in[15];
    const int*   eidx   = (const int*)d_in[16];
    const int*   batch  = (const int*)d_in[17];
    const int* esrc = eidx;
    const int* edst = eidx + N_EDGES;
    float* out = (float*)d_out;

    // workspace layout (bytes)
    char* ws = (char*)d_ws;
    float* agg   = (float*)(ws);                  // 4,800,000
    int*   deg   = (int*)  (ws + 4800000);        //   200,000
    float* qstar = (float*)(ws + 5000000);        //   196,608
    float* h0    = (float*)(ws + 5196608);        // 4 x 98,304
    float* c0    = h0 + 24576;
    float* h1    = c0 + 24576;
    float* c1    = h1 + 24576;
    float* ebuf  = (float*)(ws + 5589824);        //   200,000
    float* x1    = (float*)(ws + 5789824);        // 4,800,000
    float* x2    = (float*)(ws + 10589824);       // 4,800,000
    f16*   Bz    = (f16*)  (ws + 15389824);       //   198,656 swizzled f16 w2+b2

    // zero: agg, deg, qstar, h0/c0/h1/c1
    hipMemsetAsync(ws, 0, 5589824, stream);

    deg_kernel<<<(N_EDGES + 255) / 256, 256, 0, stream>>>(edst, deg);
    bz_kernel<<<(97 * 2 * 64 * 8 + 255) / 256, 256, 0, stream>>>(w_e2, b_e2, Bz);

    // layer 1 (fused edge-MLP + message + scatter; no W materialization)
    conv_kernel<<<(N_EDGES + 127) / 128, 256, 0, stream>>>(x, ea, w_e1, b_e1, Bz, esrc, edst, agg);
    combine_kernel<<<(N_NODES * DIM + 255) / 256, 256, 0, stream>>>(x, agg, deg, root, bias_c, x1, 1);

    // layer 2
    hipMemsetAsync(agg, 0, 4800000, stream);
    conv_kernel<<<(N_EDGES + 127) / 128, 256, 0, stream>>>(x1, ea, w_e1, b_e1, Bz, esrc, edst, agg);
    combine_kernel<<<(N_NODES * DIM + 255) / 256, 256, 0, stream>>>(x1, agg, deg, root, bias_c, x2, 0);

    // Set2Set: 3 iterations
    float *hA = h0, *cA = c0, *hB = h1, *cB = c1;
    for (int it = 0; it < 3; ++it) {
        lstm_kernel<<<(N_GRAPHS * DIM + 255) / 256, 256, 0, stream>>>(
            qstar, hA, cA, w_ih, w_hh, b_ih, b_hh, hB, cB);
        attn_kernel<<<N_GRAPHS, 64, 0, stream>>>(x2, batch, hB, qstar, ebuf);
        float* th = hA; hA = hB; hB = th;
        float* tc = cA; cA = cB; cB = tc;
    }

    head_kernel<<<(N_GRAPHS + 255) / 256, 256, 0, stream>>>(qstar, w_fc2, b_fc2, w_fc3, b_fc3, out);
}